// Round 1
// 700.414 us; speedup vs baseline: 1.0369x; 1.0369x over previous
//
#include <hip/hip_runtime.h>
#include <math.h>

#define N 4096
#define D 512
#define L 128

// ---------------- fast path (needs ~144 MB ws) ----------------
#define DTI 128
#define DTJ 256
#define DKD 16            // dbuf chunk
#define NCH (D / DKD)     // 32 chunks
#define DAS 132           // A LDS stride (2-way write banks, free)
#define DBS 284           // B LDS stride; mult of 4 (aligned b128), 284%32=28
                          // -> staging write banks 16*c4 spread = 2-way (free)
#define BUF_FLOATS (DKD * DAS + DKD * DBS)   // 6656 floats = 26624 B; x2 = 53248 B

// ---------------- fallback path (R3, ~25 MB ws) ----------------
#define PARTS 16
#define PARTJ (N / PARTS)
#define TI 128
#define TJ 64
#define KD 32
#define AS_STRIDE (TI + 4)
#define BS_STRIDE (TJ + 4)
#define DS_STRIDE (TJ + 4)
#define SMEM_FLOATS (TI * DS_STRIDE)

// acc += |t| in exactly one VOP3 instr (abs input modifier).
#define ACC_ABS(accv, t) \
  asm("v_add_f32 %0, %0, abs(%1)" : "+v"(accv) : "v"(t))

// Insert v into ascending sorted tk[0..15], dropping the old max.
__device__ __forceinline__ void topk_insert(float (&tk)[16], float v) {
  float x = v;
#pragma unroll
  for (int k = 0; k < 16; ++k) {
    float lo = fminf(x, tk[k]);
    float hi = fmaxf(x, tk[k]);
    tk[k] = lo;
    x = hi;
  }
}

// rec = latent @ W + b ; grid (N/8, 2), block 256.
__global__ __launch_bounds__(256) void linear_kernel(
    const float* __restrict__ lat_test, const float* __restrict__ lat_train,
    const float* __restrict__ W, const float* __restrict__ bias,
    float* __restrict__ rec_test, float* __restrict__ rec_train) {
  const float* __restrict__ lat = blockIdx.y ? lat_train : lat_test;
  float* __restrict__ out = blockIdx.y ? rec_train : rec_test;
  const int r0 = blockIdx.x * 8;
  const int t = threadIdx.x;

  __shared__ float ls[8 * L];
  {
    float4 v = *(const float4*)(lat + (size_t)r0 * L + t * 4);
    *(float4*)&ls[t * 4] = v;
  }
  __syncthreads();

  float acc[8][2];
#pragma unroll
  for (int r = 0; r < 8; ++r) { acc[r][0] = 0.f; acc[r][1] = 0.f; }

#pragma unroll 4
  for (int l = 0; l < L; ++l) {
    float w0 = W[l * D + t];
    float w1 = W[l * D + t + 256];
#pragma unroll
    for (int r = 0; r < 8; ++r) {
      float x = ls[r * L + l];
      acc[r][0] = fmaf(x, w0, acc[r][0]);
      acc[r][1] = fmaf(x, w1, acc[r][1]);
    }
  }
  float b0 = bias[t], b1 = bias[t + 256];
#pragma unroll
  for (int r = 0; r < 8; ++r) {
    out[(size_t)(r0 + r) * D + t] = acc[r][0] + b0;
    out[(size_t)(r0 + r) * D + t + 256] = acc[r][1] + b1;
  }
}

// ============ FAST PATH ============
// L1 cdist, 128x256 tile, 8x16/thread, software-pipelined LDS double-buffer:
// prefetch chunk k+1 into regs BEFORE computing chunk k, store to alt buffer
// after — one barrier per chunk, no vmcnt drain at the barrier.
// Column mapping: thread tx owns cols {4tx, 4tx+64, 4tx+128, 4tx+192};
// LDS col swizzle jw = j + 4*(j>>5) -> read offsets boff + 72*s, banks 2-way.
__global__ __launch_bounds__(256) __attribute__((amdgpu_waves_per_eu(2, 2)))
void dist_kernel(const float* __restrict__ Arec, const float* __restrict__ Bgt,
                 const float* __restrict__ Btr, float* __restrict__ dist) {
  const int i0 = blockIdx.x * DTI;
  const int j0 = blockIdx.y * DTJ;
  const int mat = blockIdx.z;
  const float* __restrict__ B = mat ? Btr : Bgt;
  float* __restrict__ out = dist + (size_t)mat * N * N;

  __shared__ float smem[2][BUF_FLOATS];  // 53248 B

  const int tid = threadIdx.x;
  const int tx = tid & 15;
  const int ty = tid >> 4;               // 0..15 -> 8 rows each
  const int aoff = 8 * ty;
  const int boff = 4 * tx + 4 * (tx >> 3);  // swizzled base; +72 per s

  // staging map: A chunk = 128 rows x 16 d = 512 float4 (2/thread);
  //              B chunk = 256 rows x 16 d = 1024 float4 (4/thread)
  const int r0 = tid >> 2;        // 0..63
  const int c4 = tid & 3;         // float4 index within 16-d chunk
  const int jw0 = r0 + 4 * (r0 >> 5);  // swizzled B column; +72 per 64 rows
  const float* apA0 = Arec + (size_t)(i0 + r0) * D + c4 * 4;
  const float* apA1 = Arec + (size_t)(i0 + r0 + 64) * D + c4 * 4;
  const float* bp0 = B + (size_t)(j0 + r0) * D + c4 * 4;
  const float* bp1 = B + (size_t)(j0 + r0 + 64) * D + c4 * 4;
  const float* bp2 = B + (size_t)(j0 + r0 + 128) * D + c4 * 4;
  const float* bp3 = B + (size_t)(j0 + r0 + 192) * D + c4 * 4;

  float acc[8][16];
#pragma unroll
  for (int r = 0; r < 8; ++r)
#pragma unroll
    for (int c = 0; c < 16; ++c) acc[r][c] = 0.f;

  float4 va0, va1, vb0, vb1, vb2, vb3;

#define STAGE_LOAD(off)                      \
  {                                          \
    va0 = *(const float4*)(apA0 + (off));    \
    va1 = *(const float4*)(apA1 + (off));    \
    vb0 = *(const float4*)(bp0 + (off));     \
    vb1 = *(const float4*)(bp1 + (off));     \
    vb2 = *(const float4*)(bp2 + (off));     \
    vb3 = *(const float4*)(bp3 + (off));     \
  }

#define STAGE_STORE(buf)                          \
  {                                               \
    float* As_ = (buf);                           \
    float* Bs_ = As_ + DKD * DAS;                 \
    As_[(4 * c4 + 0) * DAS + r0] = va0.x;         \
    As_[(4 * c4 + 1) * DAS + r0] = va0.y;         \
    As_[(4 * c4 + 2) * DAS + r0] = va0.z;         \
    As_[(4 * c4 + 3) * DAS + r0] = va0.w;         \
    As_[(4 * c4 + 0) * DAS + r0 + 64] = va1.x;    \
    As_[(4 * c4 + 1) * DAS + r0 + 64] = va1.y;    \
    As_[(4 * c4 + 2) * DAS + r0 + 64] = va1.z;    \
    As_[(4 * c4 + 3) * DAS + r0 + 64] = va1.w;    \
    Bs_[(4 * c4 + 0) * DBS + jw0] = vb0.x;        \
    Bs_[(4 * c4 + 1) * DBS + jw0] = vb0.y;        \
    Bs_[(4 * c4 + 2) * DBS + jw0] = vb0.z;        \
    Bs_[(4 * c4 + 3) * DBS + jw0] = vb0.w;        \
    Bs_[(4 * c4 + 0) * DBS + jw0 + 72] = vb1.x;   \
    Bs_[(4 * c4 + 1) * DBS + jw0 + 72] = vb1.y;   \
    Bs_[(4 * c4 + 2) * DBS + jw0 + 72] = vb1.z;   \
    Bs_[(4 * c4 + 3) * DBS + jw0 + 72] = vb1.w;   \
    Bs_[(4 * c4 + 0) * DBS + jw0 + 144] = vb2.x;  \
    Bs_[(4 * c4 + 1) * DBS + jw0 + 144] = vb2.y;  \
    Bs_[(4 * c4 + 2) * DBS + jw0 + 144] = vb2.z;  \
    Bs_[(4 * c4 + 3) * DBS + jw0 + 144] = vb2.w;  \
    Bs_[(4 * c4 + 0) * DBS + jw0 + 216] = vb3.x;  \
    Bs_[(4 * c4 + 1) * DBS + jw0 + 216] = vb3.y;  \
    Bs_[(4 * c4 + 2) * DBS + jw0 + 216] = vb3.z;  \
    Bs_[(4 * c4 + 3) * DBS + jw0 + 216] = vb3.w;  \
  }

  // prologue: load chunk 0 and store into buffer 0
  STAGE_LOAD(0);
  STAGE_STORE(smem[0]);

#pragma unroll 1
  for (int chunk = 0; chunk < NCH; ++chunk) {
    __syncthreads();  // buf[chunk&1] fully staged for everyone
    // prefetch chunk+1 into regs (latency covered by 16-d compute below)
    if (chunk + 1 < NCH) {
      const int off = (chunk + 1) * DKD;
      STAGE_LOAD(off);
    }

    const float* As = smem[chunk & 1];
    const float* Bs = As + DKD * DAS;
#pragma unroll 2
    for (int d = 0; d < DKD; ++d) {
      float4 a0 = *(const float4*)&As[d * DAS + aoff];
      float4 a1 = *(const float4*)&As[d * DAS + aoff + 4];
      float4 b0 = *(const float4*)&Bs[d * DBS + boff];
      float4 b1 = *(const float4*)&Bs[d * DBS + boff + 72];
      float4 b2 = *(const float4*)&Bs[d * DBS + boff + 144];
      float4 b3 = *(const float4*)&Bs[d * DBS + boff + 216];
#define ROWC(r, av)                                         \
  {                                                         \
    float t0 = av - b0.x;  ACC_ABS(acc[r][0], t0);          \
    float t1 = av - b0.y;  ACC_ABS(acc[r][1], t1);          \
    float t2 = av - b0.z;  ACC_ABS(acc[r][2], t2);          \
    float t3 = av - b0.w;  ACC_ABS(acc[r][3], t3);          \
    float t4 = av - b1.x;  ACC_ABS(acc[r][4], t4);          \
    float t5 = av - b1.y;  ACC_ABS(acc[r][5], t5);          \
    float t6 = av - b1.z;  ACC_ABS(acc[r][6], t6);          \
    float t7 = av - b1.w;  ACC_ABS(acc[r][7], t7);          \
    float t8 = av - b2.x;  ACC_ABS(acc[r][8], t8);          \
    float t9 = av - b2.y;  ACC_ABS(acc[r][9], t9);          \
    float ta = av - b2.z;  ACC_ABS(acc[r][10], ta);         \
    float tb = av - b2.w;  ACC_ABS(acc[r][11], tb);         \
    float tc = av - b3.x;  ACC_ABS(acc[r][12], tc);         \
    float td = av - b3.y;  ACC_ABS(acc[r][13], td);         \
    float te = av - b3.z;  ACC_ABS(acc[r][14], te);         \
    float tf = av - b3.w;  ACC_ABS(acc[r][15], tf);         \
  }
      ROWC(0, a0.x) ROWC(1, a0.y) ROWC(2, a0.z) ROWC(3, a0.w)
      ROWC(4, a1.x) ROWC(5, a1.y) ROWC(6, a1.z) ROWC(7, a1.w)
#undef ROWC
    }

    // store prefetched regs into the other buffer (its last readers were in
    // the previous iteration's compute, separated by this iter's barrier)
    if (chunk + 1 < NCH) {
      STAGE_STORE(smem[(chunk + 1) & 1]);
    }
  }

#pragma unroll
  for (int r = 0; r < 8; ++r) {
    float* dst = out + (size_t)(i0 + 8 * ty + r) * N + j0 + 4 * tx;
    *(float4*)(dst) = make_float4(acc[r][0], acc[r][1], acc[r][2], acc[r][3]);
    *(float4*)(dst + 64) = make_float4(acc[r][4], acc[r][5], acc[r][6], acc[r][7]);
    *(float4*)(dst + 128) = make_float4(acc[r][8], acc[r][9], acc[r][10], acc[r][11]);
    *(float4*)(dst + 192) = make_float4(acc[r][12], acc[r][13], acc[r][14], acc[r][15]);
  }
#undef STAGE_LOAD
#undef STAGE_STORE
}

// One WAVE per row (4 rows per 256-block, grid 2N/4): insert-filtered scan of
// 64 elems/lane, then 6 shfl_xor bitonic merge levels. No LDS, no barriers.
__global__ __launch_bounds__(256) void row_topk_kernel(
    const float* __restrict__ dist, float* __restrict__ scores) {
  const int wave = threadIdx.x >> 6;
  const int lane = threadIdx.x & 63;
  const int row = blockIdx.x * 4 + wave;
  const float* __restrict__ p = dist + (size_t)row * N;

  float tk[16];
#pragma unroll
  for (int k = 0; k < 16; ++k) tk[k] = 3.0e38f;

#pragma unroll 1
  for (int q = 0; q < 16; ++q) {  // each q: wave reads 1 KB contiguous
    float4 v = *(const float4*)(p + q * 256 + lane * 4);
    if (v.x < tk[15]) topk_insert(tk, v.x);
    if (v.y < tk[15]) topk_insert(tk, v.y);
    if (v.z < tk[15]) topk_insert(tk, v.z);
    if (v.w < tk[15]) topk_insert(tk, v.w);
  }

  // recursive-doubling merge: after level m, lanes in each 2m-group identical
#pragma unroll
  for (int m = 1; m < 64; m <<= 1) {
    float oth[16];
#pragma unroll
    for (int k = 0; k < 16; ++k) oth[k] = __shfl_xor(tk[k], m, 64);
    // half-cleaner: lowest 16 of union, result is bitonic
    float lo[16];
#pragma unroll
    for (int k = 0; k < 16; ++k) lo[k] = fminf(tk[k], oth[15 - k]);
    // bitonic sort of a bitonic 16-seq: stages 8,4,2,1 (constant-indexed)
#pragma unroll
    for (int dlt = 8; dlt >= 1; dlt >>= 1) {
#pragma unroll
      for (int i = 0; i < 16; ++i) {
        if ((i & dlt) == 0 && (i + dlt) < 16) {
          float a = lo[i], b = lo[i + dlt];
          lo[i] = fminf(a, b);
          lo[i + dlt] = fmaxf(a, b);
        }
      }
    }
#pragma unroll
    for (int k = 0; k < 16; ++k) tk[k] = lo[k];
  }

  if (lane == 0) {
    float s = 0.f;
#pragma unroll
    for (int k = 0; k < 16; ++k) s += 1.0f / tk[k];
    scores[row] = s * (1.0f / 16.0f);
  }
}

// ============ FALLBACK PATH (R3, proven) ============
__global__ __launch_bounds__(256) void dist_topk_kernel(
    const float* __restrict__ Arec, const float* __restrict__ Bgt,
    const float* __restrict__ Btr, float* __restrict__ cand) {
  const int itile = blockIdx.x;
  const int part = blockIdx.y;
  const int mat = blockIdx.z;
  const float* __restrict__ B = mat ? Btr : Bgt;
  const int i0 = itile * TI;
  const int jbase = part * PARTJ;

  __shared__ float smem[SMEM_FLOATS];
  float* As = smem;
  float* Bs = smem + KD * AS_STRIDE;
  float* distS = smem;

  const int tid = threadIdx.x;
  const int tx = tid & 15;
  const int ty = tid >> 4;
  const int srow = tid >> 1;
  const int shalf = tid & 1;
  const int scol = shalf * 32;

  float tk[16];
#pragma unroll
  for (int k = 0; k < 16; ++k) tk[k] = 3.0e38f;

  for (int jc = 0; jc < PARTJ; jc += TJ) {
    float acc[8][4];
#pragma unroll
    for (int r = 0; r < 8; ++r)
#pragma unroll
      for (int c = 0; c < 4; ++c) acc[r][c] = 0.f;

    for (int d0 = 0; d0 < D; d0 += KD) {
      __syncthreads();
#pragma unroll
      for (int s = 0; s < 4; ++s) {
        int f4 = tid + s * 256;
        int r = f4 >> 3;
        int c4 = f4 & 7;
        float4 v = *(const float4*)(Arec + (size_t)(i0 + r) * D + d0 + c4 * 4);
        As[(4 * c4 + 0) * AS_STRIDE + r] = v.x;
        As[(4 * c4 + 1) * AS_STRIDE + r] = v.y;
        As[(4 * c4 + 2) * AS_STRIDE + r] = v.z;
        As[(4 * c4 + 3) * AS_STRIDE + r] = v.w;
      }
#pragma unroll
      for (int s = 0; s < 2; ++s) {
        int f4 = tid + s * 256;
        int r = f4 >> 3;
        int c4 = f4 & 7;
        float4 v = *(const float4*)(B + (size_t)(jbase + jc + r) * D + d0 + c4 * 4);
        Bs[(4 * c4 + 0) * BS_STRIDE + r] = v.x;
        Bs[(4 * c4 + 1) * BS_STRIDE + r] = v.y;
        Bs[(4 * c4 + 2) * BS_STRIDE + r] = v.z;
        Bs[(4 * c4 + 3) * BS_STRIDE + r] = v.w;
      }
      __syncthreads();

#pragma unroll
      for (int d = 0; d < KD; ++d) {
        float4 a0 = *(const float4*)&As[d * AS_STRIDE + 8 * ty];
        float4 a1 = *(const float4*)&As[d * AS_STRIDE + 8 * ty + 4];
        float4 bv4 = *(const float4*)&Bs[d * BS_STRIDE + 4 * tx];
        float av[8] = {a0.x, a0.y, a0.z, a0.w, a1.x, a1.y, a1.z, a1.w};
        float bv[4] = {bv4.x, bv4.y, bv4.z, bv4.w};
#pragma unroll
        for (int r = 0; r < 8; ++r)
#pragma unroll
          for (int c = 0; c < 4; ++c) acc[r][c] += __builtin_fabsf(av[r] - bv[c]);
      }
    }

    __syncthreads();
#pragma unroll
    for (int r = 0; r < 8; ++r)
      *(float4*)&distS[(8 * ty + r) * DS_STRIDE + 4 * tx] =
          make_float4(acc[r][0], acc[r][1], acc[r][2], acc[r][3]);
    __syncthreads();

#pragma unroll 1
    for (int j4 = 0; j4 < 8; ++j4) {
      float4 v = *(const float4*)&distS[srow * DS_STRIDE + scol + j4 * 4];
      if (v.x < tk[15]) topk_insert(tk, v.x);
      if (v.y < tk[15]) topk_insert(tk, v.y);
      if (v.z < tk[15]) topk_insert(tk, v.z);
      if (v.w < tk[15]) topk_insert(tk, v.w);
    }
  }

  __syncthreads();
  float* mergeS = smem;
#pragma unroll
  for (int k4 = 0; k4 < 4; ++k4)
    *(float4*)&mergeS[srow * 32 + shalf * 16 + k4 * 4] =
        make_float4(tk[k4 * 4], tk[k4 * 4 + 1], tk[k4 * 4 + 2], tk[k4 * 4 + 3]);
  __syncthreads();

  if (tid < TI) {
    const float* LA = &mergeS[tid * 32];
    const float* LB = LA + 16;
    const int row = i0 + tid;
    float* dst = cand + ((size_t)((mat * PARTS + part) * N) + row) * 16;
    int ia = 0, ib = 0;
#pragma unroll 1
    for (int k = 0; k < 16; ++k) {
      float a = LA[ia < 16 ? ia : 15];
      float b = LB[ib < 16 ? ib : 15];
      bool takeA = (ib >= 16) || (ia < 16 && a <= b);
      dst[k] = takeA ? a : b;
      ia += takeA ? 1 : 0;
      ib += takeA ? 0 : 1;
    }
  }
}

__global__ __launch_bounds__(256) void merge_kernel(
    const float* __restrict__ cand, float* __restrict__ scores) {
  const int gid = blockIdx.x * 256 + threadIdx.x;
  if (gid >= 2 * N) return;
  const int m = gid >> 12;
  const int row = gid & (N - 1);

  float tk[16];
#pragma unroll
  for (int k = 0; k < 16; ++k) tk[k] = 3.0e38f;

  for (int p = 0; p < PARTS; ++p) {
    const float* lp = cand + ((size_t)((m * PARTS + p) * N) + row) * 16;
#pragma unroll 1
    for (int k = 0; k < 16; ++k) {
      float v = lp[k];
      if (v >= tk[15]) break;
      topk_insert(tk, v);
    }
  }
  float s = 0.f;
#pragma unroll
  for (int k = 0; k < 16; ++k) s += 1.0f / tk[k];
  scores[(size_t)m * N + row] = s * (1.0f / 16.0f);
}

// losses = relu(neg - pos); huber(delta=1) vs 0; mean. Single block.
__global__ __launch_bounds__(256) void loss_kernel(
    const float* __restrict__ scores, float* __restrict__ out) {
  const int tid = threadIdx.x;
  float s = 0.f;
  for (int i = tid; i < N; i += 256) {
    float l = scores[N + i] - scores[i];
    l = fmaxf(l, 0.f);
    s += (l <= 1.f) ? 0.5f * l * l : (l - 0.5f);
  }
#pragma unroll
  for (int off = 32; off > 0; off >>= 1) s += __shfl_down(s, off, 64);
  __shared__ float ws[4];
  if ((tid & 63) == 0) ws[tid >> 6] = s;
  __syncthreads();
  if (tid == 0) {
    float t = ws[0] + ws[1] + ws[2] + ws[3];
    out[0] = t * (1.0f / (float)N);
  }
}

extern "C" void kernel_launch(void* const* d_in, const int* in_sizes, int n_in,
                              void* d_out, int out_size, void* d_ws, size_t ws_size,
                              hipStream_t stream) {
  const float* gt_vals = (const float*)d_in[0];
  const float* train_latent = (const float*)d_in[1];
  const float* test_latent = (const float*)d_in[2];
  const float* W = (const float*)d_in[3];
  const float* b = (const float*)d_in[4];
  float* out = (float*)d_out;

  char* ws = (char*)d_ws;
  const size_t REC = 8388608;          // 8 MB each
  const size_t DIST = 134217728;       // 128 MB
  const size_t NEED_FAST = 2 * REC + DIST + 32768;

  float* rec_test = (float*)(ws);
  float* rec_train = (float*)(ws + REC);

  linear_kernel<<<dim3(N / 8, 2), 256, 0, stream>>>(
      test_latent, train_latent, W, b, rec_test, rec_train);

  if (ws_size >= NEED_FAST) {
    float* dist = (float*)(ws + 2 * REC);
    float* scores = (float*)(ws + 2 * REC + DIST);
    dist_kernel<<<dim3(N / DTI, N / DTJ, 2), 256, 0, stream>>>(
        rec_test, gt_vals, rec_train, dist);
    row_topk_kernel<<<(2 * N) / 4, 256, 0, stream>>>(dist, scores);
    loss_kernel<<<1, 256, 0, stream>>>(scores, out);
  } else {
    float* cand = (float*)(ws + 2 * REC);                 // 8 MB
    float* scores = (float*)(ws + 2 * REC + 8388608);     // 32 KB
    dist_topk_kernel<<<dim3(N / TI, PARTS, 2), 256, 0, stream>>>(
        rec_test, gt_vals, rec_train, cand);
    merge_kernel<<<(2 * N) / 256, 256, 0, stream>>>(cand, scores);
    loss_kernel<<<1, 256, 0, stream>>>(scores, out);
  }
}